// Round 10
// baseline (137.538 us; speedup 1.0000x reference)
//
#include <hip/hip_runtime.h>

#define S_LEN 2048
#define D_MODEL 1024
#define NH 16
#define BATCH 2
#define M_TOK 4096  // BATCH * S_LEN

typedef _Float16 f16;
typedef __attribute__((ext_vector_type(8))) _Float16 f16x8;
typedef __attribute__((ext_vector_type(4))) _Float16 f16x4;
typedef __attribute__((ext_vector_type(4))) float f32x4;
typedef __attribute__((ext_vector_type(16))) float f32x16;
typedef __attribute__((ext_vector_type(2))) unsigned int uint2v;

__device__ __forceinline__ void gl_lds16(const f16* g, f16* l) {
  __builtin_amdgcn_global_load_lds(
      (const __attribute__((address_space(1))) void*)g,
      (__attribute__((address_space(3))) void*)l, 16, 0, 0);
}

// ---------------- fused fp32 -> f16 convert for all 7 tensors ----------------
__global__ void cvt_all_kernel(
    const float* __restrict__ q, const float* __restrict__ k, const float* __restrict__ v,
    const float* __restrict__ Wq, const float* __restrict__ Wk,
    const float* __restrict__ Wv, const float* __restrict__ Wo,
    f16* __restrict__ qb, f16* __restrict__ kb, f16* __restrict__ vb,
    f16* __restrict__ Wqh, f16* __restrict__ Wkh, f16* __restrict__ Wvh,
    f16* __restrict__ Woh) {
  const int NX = (M_TOK * D_MODEL) / 4;    // float4 count per activation
  const int NW = (D_MODEL * D_MODEL) / 4;  // per weight
  const int total = 3 * NX + 4 * NW;
  int stride = gridDim.x * blockDim.x;
  for (int i = blockIdx.x * blockDim.x + threadIdx.x; i < total; i += stride) {
    const float* src; f16* dst; int off;
    if (i < 3 * NX) {
      int ts = i / NX; off = i - ts * NX;
      src = ts == 0 ? q : ts == 1 ? k : v;
      dst = ts == 0 ? qb : ts == 1 ? kb : vb;
    } else {
      int j = i - 3 * NX;
      int ts = j / NW; off = j - ts * NW;
      src = ts == 0 ? Wq : ts == 1 ? Wk : ts == 2 ? Wv : Wo;
      dst = ts == 0 ? Wqh : ts == 1 ? Wkh : ts == 2 ? Wvh : Woh;
    }
    float4 vv = ((const float4*)src)[off];
    union { f16 h[4]; uint2 u; } o;
    o.h[0] = (f16)vv.x; o.h[1] = (f16)vv.y; o.h[2] = (f16)vv.z; o.h[3] = (f16)vv.w;
    ((uint2*)dst)[off] = o.u;
  }
}

// ---------------- RoPE sin/cos tables: [S][32] ----------------
__global__ void rope_table_kernel(float* __restrict__ sin_t, float* __restrict__ cos_t) {
  int idx = blockIdx.x * blockDim.x + threadIdx.x;  // S*32 threads
  int s = idx >> 5, i = idx & 31;
  float inv = powf(10000.0f, -(float)i * (1.0f / 16.0f));
  float ang = (float)s * inv;
  sin_t[idx] = sinf(ang);
  cos_t[idx] = cosf(ang);
}

// LDS swizzle (T2): LDS (row R, 16B-unit U) holds global unit U ^ ((R>>1)&3).
// Staging: pre-swizzle the per-lane GLOBAL unit (dest stays linear — m104);
// lane l covers row t>>2, so source unit = (t&3) ^ ((t>>3)&3)  [lane-constant].
// Read: lk' = ((l>>4) ^ ((l>>1)&3)) * 8. 16 lanes then span all 32 banks
// exactly 2x (2-way aliasing = free) instead of 8-way on 4 banks.

// ---------------- fused Q/K/V projection GEMM (2-phase pipelined) ----------
// C[M,N] = A[M,K] * W[N,K]^T + bias. 128x128 tile, BK=32, 4 waves, dbuf LDS.
// blockIdx.z epilogues:
//   0 = Q + RoPE -> row-major [B,H,S,64]
//   1 = K + RoPE -> fragment-linear [B,H,S/32,4(ks),32(k),16(d)]
//   2 = V        -> fragment-linear [B,H,S/16,64(d),16(k)]
__global__ __launch_bounds__(256) void qkv_gemm_kernel(
    const f16* __restrict__ qb, const f16* __restrict__ kb, const f16* __restrict__ vb,
    const f16* __restrict__ Wqh, const f16* __restrict__ Wkh, const f16* __restrict__ Wvh,
    const float* __restrict__ bq, const float* __restrict__ bk, const float* __restrict__ bv,
    f16* __restrict__ Qh, f16* __restrict__ Kt, f16* __restrict__ Vt,
    const float* __restrict__ sin_t, const float* __restrict__ cos_t) {
  constexpr int K = D_MODEL;
  const int z = blockIdx.z;
  const f16* A = z == 0 ? qb : z == 1 ? kb : vb;
  const f16* Bm = z == 0 ? Wqh : z == 1 ? Wkh : Wvh;
  const float* bias = z == 0 ? bq : z == 1 ? bk : bv;

  __shared__ f16 As[2][128 * 32];
  __shared__ f16 Bs[2][128 * 32];
  const int t = threadIdx.x, w = t >> 6, l = t & 63;
  const int bm = blockIdx.x, bn = blockIdx.y;
  const int wr = w >> 1, wc = w & 1;
  const int lr = l & 15;
  const int lkp = (((l >> 4) ^ ((l >> 1) & 3)) * 8);  // swizzled read unit

  f32x4 acc[4][4] = {};

  const int su = (((t & 3) ^ ((t >> 3) & 3)) * 8);    // swizzled source unit
  const f16* gA = A + (size_t)(bm * 128 + (t >> 2)) * K + su;
  const f16* gB = Bm + (size_t)(bn * 128 + (t >> 2)) * K + su;

  auto stage = [&](int buf, int koff) {
    f16* a0 = buf ? &As[1][w * 512] : &As[0][w * 512];
    f16* b0 = buf ? &Bs[1][w * 512] : &Bs[0][w * 512];
    gl_lds16(gA + koff, a0);
    gl_lds16(gA + koff + (size_t)64 * K, a0 + 2048);
    gl_lds16(gB + koff, b0);
    gl_lds16(gB + koff + (size_t)64 * K, b0 + 2048);
  };

  stage(0, 0);
  __syncthreads();
  for (int ti = 0; ti < 32; ++ti) {
    int cur = ti & 1;
    if (ti + 1 < 32) stage(cur ^ 1, (ti + 1) * 32);  // overlap with compute below
    const f16* Ab = cur ? As[1] : As[0];
    const f16* Bb = cur ? Bs[1] : Bs[0];
    f16x8 af[4], bf[4];
#pragma unroll
    for (int m = 0; m < 4; m++) af[m] = *(const f16x8*)&Ab[(wr * 64 + m * 16 + lr) * 32 + lkp];
#pragma unroll
    for (int n = 0; n < 4; n++) bf[n] = *(const f16x8*)&Bb[(wc * 64 + n * 16 + lr) * 32 + lkp];
#pragma unroll
    for (int m = 0; m < 4; m++)
#pragma unroll
      for (int n = 0; n < 4; n++)
        acc[m][n] = __builtin_amdgcn_mfma_f32_16x16x32_f16(af[m], bf[n], acc[m][n], 0, 0, 0);
    __syncthreads();
  }

  // epilogue: C layout per 16x16 tile: col = lane&15, row = (lane>>4)*4 + j
#pragma unroll
  for (int m = 0; m < 4; m++) {
    int rbase = bm * 128 + wr * 64 + m * 16 + ((l >> 4) << 2);
#pragma unroll
    for (int n = 0; n < 4; n++) {
      int c = bn * 128 + wc * 64 + n * 16 + lr;
      float bv_ = bias[c];
#pragma unroll
      for (int j = 0; j < 4; j++) {
        float x = acc[m][n][j] + bv_;
        int rr = rbase + j;
        int b = rr >> 11, s = rr & (S_LEN - 1);
        int h = c >> 6, dk = c & 63;
        int bh = b * NH + h;
        if (z == 2) {
          // V^T fragment-linear: [bh][s/16][dk][s%16]
          Vt[((((size_t)bh * (S_LEN / 16) + (s >> 4)) * 64) + dk) * 16 + (s & 15)] = (f16)x;
        } else {
          float p = __shfl_xor(x, 1);  // pair partner (col ^ 1)
          float sv = sin_t[s * 32 + (dk >> 1)];
          float cv = cos_t[s * 32 + (dk >> 1)];
          float ov = (dk & 1) ? (p * sv + x * cv) : (x * cv - p * sv);
          if (z == 0) {
            Qh[(((size_t)bh) * S_LEN + s) * 64 + dk] = (f16)ov;
          } else {
            // K fragment-linear: [bh][s/32][dk/16][s%32][dk%16]
            Kt[(((((size_t)bh * 64 + (s >> 5)) * 4 + (dk >> 4)) * 32) + (s & 31)) * 16 + (dk & 15)] = (f16)ov;
          }
        }
      }
    }
  }
}

// ---------------- output GEMM: fp32 out (2-phase pipelined) ----------------
__global__ __launch_bounds__(256) void out_gemm_kernel(
    const f16* __restrict__ A, const f16* __restrict__ Bm,
    const float* __restrict__ bias, float* __restrict__ Cout) {
  constexpr int N = D_MODEL, K = D_MODEL;
  __shared__ f16 As[2][128 * 32];
  __shared__ f16 Bs[2][128 * 32];
  const int t = threadIdx.x, w = t >> 6, l = t & 63;
  const int bm = blockIdx.x, bn = blockIdx.y;
  const int wr = w >> 1, wc = w & 1;
  const int lr = l & 15;
  const int lkp = (((l >> 4) ^ ((l >> 1) & 3)) * 8);

  f32x4 acc[4][4] = {};

  const int su = (((t & 3) ^ ((t >> 3) & 3)) * 8);
  const f16* gA = A + (size_t)(bm * 128 + (t >> 2)) * K + su;
  const f16* gB = Bm + (size_t)(bn * 128 + (t >> 2)) * K + su;

  auto stage = [&](int buf, int koff) {
    f16* a0 = buf ? &As[1][w * 512] : &As[0][w * 512];
    f16* b0 = buf ? &Bs[1][w * 512] : &Bs[0][w * 512];
    gl_lds16(gA + koff, a0);
    gl_lds16(gA + koff + (size_t)64 * K, a0 + 2048);
    gl_lds16(gB + koff, b0);
    gl_lds16(gB + koff + (size_t)64 * K, b0 + 2048);
  };

  stage(0, 0);
  __syncthreads();
  for (int ti = 0; ti < 32; ++ti) {
    int cur = ti & 1;
    if (ti + 1 < 32) stage(cur ^ 1, (ti + 1) * 32);
    const f16* Ab = cur ? As[1] : As[0];
    const f16* Bb = cur ? Bs[1] : Bs[0];
    f16x8 af[4], bf[4];
#pragma unroll
    for (int m = 0; m < 4; m++) af[m] = *(const f16x8*)&Ab[(wr * 64 + m * 16 + lr) * 32 + lkp];
#pragma unroll
    for (int n = 0; n < 4; n++) bf[n] = *(const f16x8*)&Bb[(wc * 64 + n * 16 + lr) * 32 + lkp];
#pragma unroll
    for (int m = 0; m < 4; m++)
#pragma unroll
      for (int n = 0; n < 4; n++)
        acc[m][n] = __builtin_amdgcn_mfma_f32_16x16x32_f16(af[m], bf[n], acc[m][n], 0, 0, 0);
    __syncthreads();
  }

#pragma unroll
  for (int m = 0; m < 4; m++) {
    int rbase = bm * 128 + wr * 64 + m * 16 + ((l >> 4) << 2);
#pragma unroll
    for (int n = 0; n < 4; n++) {
      int c = bn * 128 + wc * 64 + n * 16 + lr;
      float bv = bias[c];
#pragma unroll
      for (int j = 0; j < 4; j++)
        Cout[(size_t)(rbase + j) * N + c] = acc[m][n][j] + bv;
    }
  }
}

// ---------------- causal flash attention, swapped-QK^T 32x32 ----------------
// Qh: [B,H,S,64]; Kt: [B,H,S/32,4,32,16]; Vt: [B,H,S/16,64,16] (all f16).
// K/V fragment loads are fully coalesced 1KB wave-loads. Grid 1024, 4 waves.
// Block owns chunk pair (cx, 63-cx): 65 tiles uniform. Waves {0,1} k-split cx;
// {2,3} k-split 63-cx; 2-way LDS merges. XCD-pinned bh.
__global__ __launch_bounds__(256, 4) void attn_kernel(
    const f16* __restrict__ Qh, const f16* __restrict__ Kt,
    const f16* __restrict__ Vt, f16* __restrict__ ctx) {
  __shared__ f16 po_lds[2][64][32];  // per pair: k-split partner partial O (f16)
  __shared__ float ml_lds[2][64];    // per pair: m[32], l[32]
  const int t = threadIdx.x, w = t >> 6, l = t & 63;
  const int lq = l & 31, hi = l >> 5;
  const int id = blockIdx.x;
  const int xcd = id & 7, slot = id >> 3;     // slot 0..127
  const int bh = (slot >> 5) * 8 + xcd;       // 4 bh per XCD
  const int b = bh >> 4, h = bh & 15;
  const int cp = slot & 31;                   // chunk-pair index
  const int pairidx = w >> 1, wk = w & 1;
  const int cx = pairidx ? (63 - cp) : cp;    // this wave-pair's q-chunk
  const int q0w = cx * 32;
  const int q = q0w + lq;
  const int ntot = cx + 1;                    // causal k-tiles for this chunk
  const int nA = (ntot + 1) >> 1;
  const int t0 = wk ? nA : 0;
  const int t1 = wk ? ntot : nA;

  const f16* Qb = Qh + ((size_t)bh * S_LEN + q0w) * 64;
  const f16* Kb = Kt + (size_t)bh * S_LEN * 64;   // tile stride 4*32*16 = 2048
  const f16* Vb = Vt + (size_t)bh * S_LEN * 64;   // kb2 stride 64*16 = 1024

  // Q as B-frag, pre-scaled by (1/8)*log2(e) -> softmax in exp2 domain
  f16x8 qf[4];
#pragma unroll
  for (int ks = 0; ks < 4; ks++) {
    qf[ks] = *(const f16x8*)(Qb + (size_t)lq * 64 + ks * 16 + hi * 8);
#pragma unroll
    for (int j = 0; j < 8; j++) qf[ks][j] *= (f16)0.18033688f;
  }

  f32x16 o[2] = {};  // O^T accum: o[dt][r] = O[d = dt*32 + (r&3)+8*(r>>2)+4*hi][q]
  float m = -1e30f, lsum = 0.f;

  auto loadK = [&](int kt, f16x8* dst) {
    const f16* kp = Kb + (size_t)kt * 2048 + lq * 16 + hi * 8;
#pragma unroll
    for (int ks = 0; ks < 4; ks++)
      dst[ks] = *(const f16x8*)(kp + ks * 512);
  };

  auto body = [&](int kt, f16x8* cur, f16x8* nxt) {
    const int k0 = kt * 32;
    loadK(kt + 1 < t1 ? kt + 1 : kt, nxt);  // prefetch next K tile
    // ---- QK^T (swapped): 4 contraction slices over DK=64
    f32x16 s = {};
#pragma unroll
    for (int ks = 0; ks < 4; ks++)
      s = __builtin_amdgcn_mfma_f32_32x32x16_f16(cur[ks], qf[ks], s, 0, 0, 0);
    // V-frags: coalesced 1KB loads, issued early (softmax covers latency)
    const f16* vp = Vb + (size_t)(k0 >> 4) * 1024 + lq * 16 + hi * 8;
    f16x8 vf00 = *(const f16x8*)(vp);                 // d=lq,    k=k0..k0+15
    f16x8 vf10 = *(const f16x8*)(vp + 512);           // d=32+lq
    f16x8 vf01 = *(const f16x8*)(vp + 1024);          // d=lq,    k=k0+16..k0+31
    f16x8 vf11 = *(const f16x8*)(vp + 1536);          // d=32+lq

    // ---- causal mask (diagonal tile only)
    if (kt == cx) {
#pragma unroll
      for (int r = 0; r < 16; r++) {
        int kk = k0 + (r & 3) + 8 * (r >> 2) + 4 * hi;
        if (kk > q) s[r] = -1e30f;
      }
    }
    // ---- online softmax (exp2 domain), balanced-tree reductions
    float a0 = fmaxf(s[0], s[1]), a1 = fmaxf(s[2], s[3]);
    float a2 = fmaxf(s[4], s[5]), a3 = fmaxf(s[6], s[7]);
    float a4 = fmaxf(s[8], s[9]), a5 = fmaxf(s[10], s[11]);
    float a6 = fmaxf(s[12], s[13]), a7 = fmaxf(s[14], s[15]);
    float b0_ = fmaxf(a0, a1), b1_ = fmaxf(a2, a3), b2_ = fmaxf(a4, a5), b3_ = fmaxf(a6, a7);
    float pmax = fmaxf(fmaxf(b0_, b1_), fmaxf(b2_, b3_));
    pmax = fmaxf(pmax, __shfl_xor(pmax, 32));
    if (!__all(pmax <= m + 11.5f)) {  // defer-max (T13), THR = 8*log2e
      float mn = fmaxf(m, pmax);
      float sc = exp2f(m - mn);
#pragma unroll
      for (int r = 0; r < 16; r++) { o[0][r] *= sc; o[1][r] *= sc; }
      lsum *= sc;
      m = mn;
    }
#pragma unroll
    for (int r = 0; r < 16; r++) s[r] = exp2f(s[r] - m);
    float c0 = (s[0] + s[1]) + (s[2] + s[3]);
    float c1 = (s[4] + s[5]) + (s[6] + s[7]);
    float c2 = (s[8] + s[9]) + (s[10] + s[11]);
    float c3 = (s[12] + s[13]) + (s[14] + s[15]);
    float rs = (c0 + c1) + (c2 + c3);
    rs += __shfl_xor(rs, 32);
    lsum += rs;

    // ---- pack P into PV B-frag: 8 cvt_pkrtz + 4 permlane32_swap
    unsigned pw[8];
#pragma unroll
    for (int i = 0; i < 8; i++)
      pw[i] = __builtin_bit_cast(unsigned, __builtin_amdgcn_cvt_pkrtz(s[2 * i], s[2 * i + 1]));
    uint2v s02 = __builtin_amdgcn_permlane32_swap(pw[0], pw[2], false, false);
    uint2v s13 = __builtin_amdgcn_permlane32_swap(pw[1], pw[3], false, false);
    uint2v s46 = __builtin_amdgcn_permlane32_swap(pw[4], pw[6], false, false);
    uint2v s57 = __builtin_amdgcn_permlane32_swap(pw[5], pw[7], false, false);
    union BU { unsigned u[4]; f16x8 v; };
    BU pb0, pb1;
    pb0.u[0] = s02[0]; pb0.u[1] = s13[0]; pb0.u[2] = s02[1]; pb0.u[3] = s13[1];
    pb1.u[0] = s46[0]; pb1.u[1] = s57[0]; pb1.u[2] = s46[1]; pb1.u[3] = s57[1];

    // ---- PV: O^T += V^T-frag x P^T-frag
    o[0] = __builtin_amdgcn_mfma_f32_32x32x16_f16(vf00, pb0.v, o[0], 0, 0, 0);
    o[0] = __builtin_amdgcn_mfma_f32_32x32x16_f16(vf01, pb1.v, o[0], 0, 0, 0);
    o[1] = __builtin_amdgcn_mfma_f32_32x32x16_f16(vf10, pb0.v, o[1], 0, 0, 0);
    o[1] = __builtin_amdgcn_mfma_f32_32x32x16_f16(vf11, pb1.v, o[1], 0, 0, 0);
  };

  f16x8 ka[4], kb_[4];
  if (t0 < t1) loadK(t0, ka);
  int kt = t0;
  for (; kt + 2 <= t1; kt += 2) { body(kt, ka, kb_); body(kt + 1, kb_, ka); }
  if (kt < t1) body(kt, ka, kb_);

  // ---- k-split partner publishes, lead wave merges + writes
  if (wk == 1) {
#pragma unroll
    for (int dt = 0; dt < 2; dt++)
#pragma unroll
      for (int r = 0; r < 16; r++)
        po_lds[pairidx][(dt * 16 + r) * 2 + hi][lq] = (f16)o[dt][r];
    if (hi == 0) { ml_lds[pairidx][lq] = m; ml_lds[pairidx][32 + lq] = lsum; }
  }
  __syncthreads();
  if (wk == 0) {
    float mB = ml_lds[pairidx][lq], lB = ml_lds[pairidx][32 + lq];
    float mf = fmaxf(m, mB);
    float sA = exp2f(m - mf), sB = exp2f(mB - mf);
    float lf = lsum * sA + lB * sB;
    float inv = 1.0f / lf;
    f16* crow = ctx + ((size_t)(b * S_LEN + q)) * D_MODEL + h * 64;
#pragma unroll
    for (int dt = 0; dt < 2; dt++) {
#pragma unroll
      for (int g = 0; g < 4; g++) {
        f16x4 ov;
#pragma unroll
        for (int c = 0; c < 4; c++) {
          int r = g * 4 + c;
          float vB = (float)po_lds[pairidx][(dt * 16 + r) * 2 + hi][lq];
          ov[c] = (f16)((o[dt][r] * sA + vB * sB) * inv);
        }
        *(f16x4*)(crow + dt * 32 + g * 8 + hi * 4) = ov;
      }
    }
  }
}

extern "C" void kernel_launch(void* const* d_in, const int* in_sizes, int n_in,
                              void* d_out, int out_size, void* d_ws, size_t ws_size,
                              hipStream_t stream) {
  const float* q = (const float*)d_in[0];
  const float* k = (const float*)d_in[1];
  const float* v = (const float*)d_in[2];
  // d_in[3] = mask (causal tril, hardcoded), d_in[4] = max_seq_len (unused)
  const float* Wq = (const float*)d_in[5];
  const float* bq = (const float*)d_in[6];
  const float* Wk = (const float*)d_in[7];
  const float* bk = (const float*)d_in[8];
  const float* Wv = (const float*)d_in[9];
  const float* bv = (const float*)d_in[10];
  const float* Wo = (const float*)d_in[11];
  const float* bo = (const float*)d_in[12];

  char* ws = (char*)d_ws;
  const size_t MB = 1ull << 20;
  f16* qb   = (f16*)(ws + 0 * MB);    // [4096,1024] f16, 8MB each
  f16* kb   = (f16*)(ws + 8 * MB);
  f16* vb   = (f16*)(ws + 16 * MB);
  f16* Wqh  = (f16*)(ws + 24 * MB);   // [1024,1024] f16, 2MB each
  f16* Wkh  = (f16*)(ws + 26 * MB);
  f16* Wvh  = (f16*)(ws + 28 * MB);
  f16* Woh  = (f16*)(ws + 30 * MB);
  f16* Qh   = (f16*)(ws + 32 * MB);   // [B,H,S,64] f16
  f16* Kt   = (f16*)(ws + 40 * MB);   // [B,H,S/32,4,32,16] f16
  f16* Vt   = (f16*)(ws + 48 * MB);   // [B,H,S/16,64,16] f16
  f16* ctxb = (f16*)(ws + 56 * MB);   // [B,S,D] f16
  float* sin_t = (float*)(ws + 64 * MB);           // [S,32] f32
  float* cos_t = (float*)(ws + 64 * MB + 256 * 1024);

  cvt_all_kernel<<<dim3(2048), dim3(256), 0, stream>>>(
      q, k, v, Wq, Wk, Wv, Wo, qb, kb, vb, Wqh, Wkh, Wvh, Woh);
  rope_table_kernel<<<dim3((S_LEN * 32) / 256), dim3(256), 0, stream>>>(sin_t, cos_t);

  qkv_gemm_kernel<<<dim3(M_TOK / 128, D_MODEL / 128, 3), 256, 0, stream>>>(
      qb, kb, vb, Wqh, Wkh, Wvh, bq, bk, bv, Qh, Kt, Vt, sin_t, cos_t);

  attn_kernel<<<dim3(1024), dim3(256), 0, stream>>>(Qh, Kt, Vt, ctxb);

  out_gemm_kernel<<<dim3(M_TOK / 128, D_MODEL / 128), 256, 0, stream>>>(ctxb, Woh, bo, (float*)d_out);
}

// Round 11
// 123.059 us; speedup vs baseline: 1.1177x; 1.1177x over previous
//
#include <hip/hip_runtime.h>

#define S_LEN 2048
#define D_MODEL 1024
#define NH 16
#define BATCH 2
#define M_TOK 4096  // BATCH * S_LEN

typedef _Float16 f16;
typedef __attribute__((ext_vector_type(8))) _Float16 f16x8;
typedef __attribute__((ext_vector_type(4))) _Float16 f16x4;
typedef __attribute__((ext_vector_type(4))) float f32x4;
typedef __attribute__((ext_vector_type(16))) float f32x16;
typedef __attribute__((ext_vector_type(2))) unsigned int uint2v;

__device__ __forceinline__ void gl_lds16(const f16* g, f16* l) {
  __builtin_amdgcn_global_load_lds(
      (const __attribute__((address_space(1))) void*)g,
      (__attribute__((address_space(3))) void*)l, 16, 0, 0);
}

// ------- fused fp32 -> f16 convert for all 7 tensors + RoPE float2 table ----
__global__ void cvt_all_kernel(
    const float* __restrict__ q, const float* __restrict__ k, const float* __restrict__ v,
    const float* __restrict__ Wq, const float* __restrict__ Wk,
    const float* __restrict__ Wv, const float* __restrict__ Wo,
    f16* __restrict__ qb, f16* __restrict__ kb, f16* __restrict__ vb,
    f16* __restrict__ Wqh, f16* __restrict__ Wkh, f16* __restrict__ Wvh,
    f16* __restrict__ Woh, float2* __restrict__ rope2) {
  const int NX = (M_TOK * D_MODEL) / 4;    // float4 count per activation
  const int NW = (D_MODEL * D_MODEL) / 4;  // per weight
  const int total = 3 * NX + 4 * NW;
  int stride = gridDim.x * blockDim.x;
  int tid0 = blockIdx.x * blockDim.x + threadIdx.x;
  // rope table: first S*32 threads also emit one (cos,sin) pair
  if (tid0 < S_LEN * 32) {
    int s = tid0 >> 5, i = tid0 & 31;
    float inv = powf(10000.0f, -(float)i * (1.0f / 16.0f));
    float ang = (float)s * inv;
    rope2[tid0] = make_float2(cosf(ang), sinf(ang));
  }
  for (int i = tid0; i < total; i += stride) {
    const float* src; f16* dst; int off;
    if (i < 3 * NX) {
      int ts = i / NX; off = i - ts * NX;
      src = ts == 0 ? q : ts == 1 ? k : v;
      dst = ts == 0 ? qb : ts == 1 ? kb : vb;
    } else {
      int j = i - 3 * NX;
      int ts = j / NW; off = j - ts * NW;
      src = ts == 0 ? Wq : ts == 1 ? Wk : ts == 2 ? Wv : Wo;
      dst = ts == 0 ? Wqh : ts == 1 ? Wkh : ts == 2 ? Wvh : Woh;
    }
    float4 vv = ((const float4*)src)[off];
    union { f16 h[4]; uint2 u; } o;
    o.h[0] = (f16)vv.x; o.h[1] = (f16)vv.y; o.h[2] = (f16)vv.z; o.h[3] = (f16)vv.w;
    ((uint2*)dst)[off] = o.u;
  }
}

// LDS swizzle (T2): LDS (row R, 16B-unit U) holds global unit U ^ ((R>>1)&3).
// Kept (conflicts 3.15M -> 0, free); see R10 notes.

// ---------------- fused Q/K/V projection GEMM (2-phase pipelined) ----------
// blockIdx.z epilogues:
//   0 = Q + RoPE -> row-major [B,H,S,64]
//   1 = K + RoPE -> fragment-linear [B,H,S/32,4(ks),32(k),16(d)]
//   2 = V        -> fragment-linear [B,H,S/16,64(d),16(k)], f16x4 stores
__global__ __launch_bounds__(256) void qkv_gemm_kernel(
    const f16* __restrict__ qb, const f16* __restrict__ kb, const f16* __restrict__ vb,
    const f16* __restrict__ Wqh, const f16* __restrict__ Wkh, const f16* __restrict__ Wvh,
    const float* __restrict__ bq, const float* __restrict__ bk, const float* __restrict__ bv,
    f16* __restrict__ Qh, f16* __restrict__ Kt, f16* __restrict__ Vt,
    const float2* __restrict__ rope2) {
  constexpr int K = D_MODEL;
  const int z = blockIdx.z;
  const f16* A = z == 0 ? qb : z == 1 ? kb : vb;
  const f16* Bm = z == 0 ? Wqh : z == 1 ? Wkh : Wvh;
  const float* bias = z == 0 ? bq : z == 1 ? bk : bv;

  __shared__ f16 As[2][128 * 32];
  __shared__ f16 Bs[2][128 * 32];
  const int t = threadIdx.x, w = t >> 6, l = t & 63;
  const int bm = blockIdx.x, bn = blockIdx.y;
  const int wr = w >> 1, wc = w & 1;
  const int lr = l & 15;
  const int lkp = (((l >> 4) ^ ((l >> 1) & 3)) * 8);  // swizzled read unit

  f32x4 acc[4][4] = {};

  const int su = (((t & 3) ^ ((t >> 3) & 3)) * 8);    // swizzled source unit
  const f16* gA = A + (size_t)(bm * 128 + (t >> 2)) * K + su;
  const f16* gB = Bm + (size_t)(bn * 128 + (t >> 2)) * K + su;

  auto stage = [&](int buf, int koff) {
    f16* a0 = buf ? &As[1][w * 512] : &As[0][w * 512];
    f16* b0 = buf ? &Bs[1][w * 512] : &Bs[0][w * 512];
    gl_lds16(gA + koff, a0);
    gl_lds16(gA + koff + (size_t)64 * K, a0 + 2048);
    gl_lds16(gB + koff, b0);
    gl_lds16(gB + koff + (size_t)64 * K, b0 + 2048);
  };

  stage(0, 0);
  __syncthreads();
  for (int ti = 0; ti < 32; ++ti) {
    int cur = ti & 1;
    if (ti + 1 < 32) stage(cur ^ 1, (ti + 1) * 32);  // overlap with compute below
    const f16* Ab = cur ? As[1] : As[0];
    const f16* Bb = cur ? Bs[1] : Bs[0];
    f16x8 af[4], bf[4];
#pragma unroll
    for (int m = 0; m < 4; m++) af[m] = *(const f16x8*)&Ab[(wr * 64 + m * 16 + lr) * 32 + lkp];
#pragma unroll
    for (int n = 0; n < 4; n++) bf[n] = *(const f16x8*)&Bb[(wc * 64 + n * 16 + lr) * 32 + lkp];
#pragma unroll
    for (int m = 0; m < 4; m++)
#pragma unroll
      for (int n = 0; n < 4; n++)
        acc[m][n] = __builtin_amdgcn_mfma_f32_16x16x32_f16(af[m], bf[n], acc[m][n], 0, 0, 0);
    __syncthreads();
  }

  // epilogue: C layout per 16x16 tile: col = lane&15, row = (lane>>4)*4 + j
#pragma unroll
  for (int m = 0; m < 4; m++) {
    int rbase = bm * 128 + wr * 64 + m * 16 + ((l >> 4) << 2);
#pragma unroll
    for (int n = 0; n < 4; n++) {
      int c = bn * 128 + wc * 64 + n * 16 + lr;
      float bv_ = bias[c];
      if (z == 2) {
        // V^T fragment-linear: [bh][s/16][dk][s%16]; j contiguous -> f16x4
        int s0 = rbase;  // s>>4 constant over j
        int b = s0 >> 11, s = s0 & (S_LEN - 1);
        int h = c >> 6, dk = c & 63;
        int bh = b * NH + h;
        f16x4 ov;
#pragma unroll
        for (int j = 0; j < 4; j++) ov[j] = (f16)(acc[m][n][j] + bv_);
        *(f16x4*)&Vt[((((size_t)bh * (S_LEN / 16) + (s >> 4)) * 64) + dk) * 16 + (s & 15)] = ov;
      } else {
#pragma unroll
        for (int j = 0; j < 4; j++) {
          float x = acc[m][n][j] + bv_;
          int rr = rbase + j;
          int b = rr >> 11, s = rr & (S_LEN - 1);
          int h = c >> 6, dk = c & 63;
          int bh = b * NH + h;
          float p = __shfl_xor(x, 1);  // pair partner (col ^ 1)
          float2 cs = rope2[s * 32 + (dk >> 1)];
          float ov = (dk & 1) ? (p * cs.y + x * cs.x) : (x * cs.x - p * cs.y);
          if (z == 0) {
            Qh[(((size_t)bh) * S_LEN + s) * 64 + dk] = (f16)ov;
          } else {
            // K fragment-linear: [bh][s/32][dk/16][s%32][dk%16]
            Kt[(((((size_t)bh * 64 + (s >> 5)) * 4 + (dk >> 4)) * 32) + (s & 31)) * 16 + (dk & 15)] = (f16)ov;
          }
        }
      }
    }
  }
}

// ---------------- output GEMM: fp32 out (2-phase pipelined) ----------------
__global__ __launch_bounds__(256) void out_gemm_kernel(
    const f16* __restrict__ A, const f16* __restrict__ Bm,
    const float* __restrict__ bias, float* __restrict__ Cout) {
  constexpr int N = D_MODEL, K = D_MODEL;
  __shared__ f16 As[2][128 * 32];
  __shared__ f16 Bs[2][128 * 32];
  const int t = threadIdx.x, w = t >> 6, l = t & 63;
  const int bm = blockIdx.x, bn = blockIdx.y;
  const int wr = w >> 1, wc = w & 1;
  const int lr = l & 15;
  const int lkp = (((l >> 4) ^ ((l >> 1) & 3)) * 8);

  f32x4 acc[4][4] = {};

  const int su = (((t & 3) ^ ((t >> 3) & 3)) * 8);
  const f16* gA = A + (size_t)(bm * 128 + (t >> 2)) * K + su;
  const f16* gB = Bm + (size_t)(bn * 128 + (t >> 2)) * K + su;

  auto stage = [&](int buf, int koff) {
    f16* a0 = buf ? &As[1][w * 512] : &As[0][w * 512];
    f16* b0 = buf ? &Bs[1][w * 512] : &Bs[0][w * 512];
    gl_lds16(gA + koff, a0);
    gl_lds16(gA + koff + (size_t)64 * K, a0 + 2048);
    gl_lds16(gB + koff, b0);
    gl_lds16(gB + koff + (size_t)64 * K, b0 + 2048);
  };

  stage(0, 0);
  __syncthreads();
  for (int ti = 0; ti < 32; ++ti) {
    int cur = ti & 1;
    if (ti + 1 < 32) stage(cur ^ 1, (ti + 1) * 32);
    const f16* Ab = cur ? As[1] : As[0];
    const f16* Bb = cur ? Bs[1] : Bs[0];
    f16x8 af[4], bf[4];
#pragma unroll
    for (int m = 0; m < 4; m++) af[m] = *(const f16x8*)&Ab[(wr * 64 + m * 16 + lr) * 32 + lkp];
#pragma unroll
    for (int n = 0; n < 4; n++) bf[n] = *(const f16x8*)&Bb[(wc * 64 + n * 16 + lr) * 32 + lkp];
#pragma unroll
    for (int m = 0; m < 4; m++)
#pragma unroll
      for (int n = 0; n < 4; n++)
        acc[m][n] = __builtin_amdgcn_mfma_f32_16x16x32_f16(af[m], bf[n], acc[m][n], 0, 0, 0);
    __syncthreads();
  }

#pragma unroll
  for (int m = 0; m < 4; m++) {
    int rbase = bm * 128 + wr * 64 + m * 16 + ((l >> 4) << 2);
#pragma unroll
    for (int n = 0; n < 4; n++) {
      int c = bn * 128 + wc * 64 + n * 16 + lr;
      float bv = bias[c];
#pragma unroll
      for (int j = 0; j < 4; j++)
        Cout[(size_t)(rbase + j) * N + c] = acc[m][n][j] + bv;
    }
  }
}

// ---------------- causal flash attention, swapped-QK^T 32x32 ----------------
// Qh: [B,H,S,64]; Kt: [B,H,S/32,4,32,16]; Vt: [B,H,S/16,64,16] (all f16).
// K/V fragment loads are fully coalesced 1KB wave-loads. Grid 1024, 4 waves.
// Block owns chunk pair (cx, 63-cx): 65 tiles uniform. Waves {0,1} k-split cx;
// {2,3} k-split 63-cx; 2-way LDS merges. XCD-pinned bh. T5 setprio on MFMA.
__global__ __launch_bounds__(256, 4) void attn_kernel(
    const f16* __restrict__ Qh, const f16* __restrict__ Kt,
    const f16* __restrict__ Vt, f16* __restrict__ ctx) {
  __shared__ f16 po_lds[2][64][32];  // per pair: k-split partner partial O (f16)
  __shared__ float ml_lds[2][64];    // per pair: m[32], l[32]
  const int t = threadIdx.x, w = t >> 6, l = t & 63;
  const int lq = l & 31, hi = l >> 5;
  const int id = blockIdx.x;
  const int xcd = id & 7, slot = id >> 3;     // slot 0..127
  const int bh = (slot >> 5) * 8 + xcd;       // 4 bh per XCD
  const int b = bh >> 4, h = bh & 15;
  const int cp = slot & 31;                   // chunk-pair index
  const int pairidx = w >> 1, wk = w & 1;
  const int cx = pairidx ? (63 - cp) : cp;    // this wave-pair's q-chunk
  const int q0w = cx * 32;
  const int q = q0w + lq;
  const int ntot = cx + 1;                    // causal k-tiles for this chunk
  const int nA = (ntot + 1) >> 1;
  const int t0 = wk ? nA : 0;
  const int t1 = wk ? ntot : nA;

  const f16* Qb = Qh + ((size_t)bh * S_LEN + q0w) * 64;
  const f16* Kb = Kt + (size_t)bh * S_LEN * 64;   // tile stride 4*32*16 = 2048
  const f16* Vb = Vt + (size_t)bh * S_LEN * 64;   // kb2 stride 64*16 = 1024

  // Q as B-frag, pre-scaled by (1/8)*log2(e) -> softmax in exp2 domain
  f16x8 qf[4];
#pragma unroll
  for (int ks = 0; ks < 4; ks++) {
    qf[ks] = *(const f16x8*)(Qb + (size_t)lq * 64 + ks * 16 + hi * 8);
#pragma unroll
    for (int j = 0; j < 8; j++) qf[ks][j] *= (f16)0.18033688f;
  }

  f32x16 o[2] = {};  // O^T accum: o[dt][r] = O[d = dt*32 + (r&3)+8*(r>>2)+4*hi][q]
  float m = -1e30f, lsum = 0.f;

  auto loadK = [&](int kt, f16x8* dst) {
    const f16* kp = Kb + (size_t)kt * 2048 + lq * 16 + hi * 8;
#pragma unroll
    for (int ks = 0; ks < 4; ks++)
      dst[ks] = *(const f16x8*)(kp + ks * 512);
  };

  auto body = [&](int kt, f16x8* cur, f16x8* nxt) {
    const int k0 = kt * 32;
    loadK(kt + 1 < t1 ? kt + 1 : kt, nxt);  // prefetch next K tile
    // ---- QK^T (swapped): 4 contraction slices over DK=64
    f32x16 s = {};
    __builtin_amdgcn_s_setprio(1);
#pragma unroll
    for (int ks = 0; ks < 4; ks++)
      s = __builtin_amdgcn_mfma_f32_32x32x16_f16(cur[ks], qf[ks], s, 0, 0, 0);
    __builtin_amdgcn_s_setprio(0);
    // V-frags: coalesced 1KB loads, issued early (softmax covers latency)
    const f16* vp = Vb + (size_t)(k0 >> 4) * 1024 + lq * 16 + hi * 8;
    f16x8 vf00 = *(const f16x8*)(vp);                 // d=lq,    k=k0..k0+15
    f16x8 vf10 = *(const f16x8*)(vp + 512);           // d=32+lq
    f16x8 vf01 = *(const f16x8*)(vp + 1024);          // d=lq,    k=k0+16..k0+31
    f16x8 vf11 = *(const f16x8*)(vp + 1536);          // d=32+lq

    // ---- causal mask (diagonal tile only)
    if (kt == cx) {
#pragma unroll
      for (int r = 0; r < 16; r++) {
        int kk = k0 + (r & 3) + 8 * (r >> 2) + 4 * hi;
        if (kk > q) s[r] = -1e30f;
      }
    }
    // ---- online softmax (exp2 domain), balanced-tree reductions
    float a0 = fmaxf(s[0], s[1]), a1 = fmaxf(s[2], s[3]);
    float a2 = fmaxf(s[4], s[5]), a3 = fmaxf(s[6], s[7]);
    float a4 = fmaxf(s[8], s[9]), a5 = fmaxf(s[10], s[11]);
    float a6 = fmaxf(s[12], s[13]), a7 = fmaxf(s[14], s[15]);
    float b0_ = fmaxf(a0, a1), b1_ = fmaxf(a2, a3), b2_ = fmaxf(a4, a5), b3_ = fmaxf(a6, a7);
    float pmax = fmaxf(fmaxf(b0_, b1_), fmaxf(b2_, b3_));
    pmax = fmaxf(pmax, __shfl_xor(pmax, 32));
    if (!__all(pmax <= m + 11.5f)) {  // defer-max (T13), THR = 8*log2e
      float mn = fmaxf(m, pmax);
      float sc = exp2f(m - mn);
#pragma unroll
      for (int r = 0; r < 16; r++) { o[0][r] *= sc; o[1][r] *= sc; }
      lsum *= sc;
      m = mn;
    }
#pragma unroll
    for (int r = 0; r < 16; r++) s[r] = exp2f(s[r] - m);
    float c0 = (s[0] + s[1]) + (s[2] + s[3]);
    float c1 = (s[4] + s[5]) + (s[6] + s[7]);
    float c2 = (s[8] + s[9]) + (s[10] + s[11]);
    float c3 = (s[12] + s[13]) + (s[14] + s[15]);
    float rs = (c0 + c1) + (c2 + c3);
    rs += __shfl_xor(rs, 32);
    lsum += rs;

    // ---- pack P into PV B-frag: 8 cvt_pkrtz + 4 permlane32_swap
    unsigned pw[8];
#pragma unroll
    for (int i = 0; i < 8; i++)
      pw[i] = __builtin_bit_cast(unsigned, __builtin_amdgcn_cvt_pkrtz(s[2 * i], s[2 * i + 1]));
    uint2v s02 = __builtin_amdgcn_permlane32_swap(pw[0], pw[2], false, false);
    uint2v s13 = __builtin_amdgcn_permlane32_swap(pw[1], pw[3], false, false);
    uint2v s46 = __builtin_amdgcn_permlane32_swap(pw[4], pw[6], false, false);
    uint2v s57 = __builtin_amdgcn_permlane32_swap(pw[5], pw[7], false, false);
    union BU { unsigned u[4]; f16x8 v; };
    BU pb0, pb1;
    pb0.u[0] = s02[0]; pb0.u[1] = s13[0]; pb0.u[2] = s02[1]; pb0.u[3] = s13[1];
    pb1.u[0] = s46[0]; pb1.u[1] = s57[0]; pb1.u[2] = s46[1]; pb1.u[3] = s57[1];

    // ---- PV: O^T += V^T-frag x P^T-frag
    __builtin_amdgcn_s_setprio(1);
    o[0] = __builtin_amdgcn_mfma_f32_32x32x16_f16(vf00, pb0.v, o[0], 0, 0, 0);
    o[0] = __builtin_amdgcn_mfma_f32_32x32x16_f16(vf01, pb1.v, o[0], 0, 0, 0);
    o[1] = __builtin_amdgcn_mfma_f32_32x32x16_f16(vf10, pb0.v, o[1], 0, 0, 0);
    o[1] = __builtin_amdgcn_mfma_f32_32x32x16_f16(vf11, pb1.v, o[1], 0, 0, 0);
    __builtin_amdgcn_s_setprio(0);
  };

  f16x8 ka[4], kb_[4];
  if (t0 < t1) loadK(t0, ka);
  int kt = t0;
  for (; kt + 2 <= t1; kt += 2) { body(kt, ka, kb_); body(kt + 1, kb_, ka); }
  if (kt < t1) body(kt, ka, kb_);

  // ---- k-split partner publishes, lead wave merges + writes
  if (wk == 1) {
#pragma unroll
    for (int dt = 0; dt < 2; dt++)
#pragma unroll
      for (int r = 0; r < 16; r++)
        po_lds[pairidx][(dt * 16 + r) * 2 + hi][lq] = (f16)o[dt][r];
    if (hi == 0) { ml_lds[pairidx][lq] = m; ml_lds[pairidx][32 + lq] = lsum; }
  }
  __syncthreads();
  if (wk == 0) {
    float mB = ml_lds[pairidx][lq], lB = ml_lds[pairidx][32 + lq];
    float mf = fmaxf(m, mB);
    float sA = exp2f(m - mf), sB = exp2f(mB - mf);
    float lf = lsum * sA + lB * sB;
    float inv = 1.0f / lf;
    f16* crow = ctx + ((size_t)(b * S_LEN + q)) * D_MODEL + h * 64;
#pragma unroll
    for (int dt = 0; dt < 2; dt++) {
#pragma unroll
      for (int g = 0; g < 4; g++) {
        f16x4 ov;
#pragma unroll
        for (int c = 0; c < 4; c++) {
          int r = g * 4 + c;
          float vB = (float)po_lds[pairidx][(dt * 16 + r) * 2 + hi][lq];
          ov[c] = (f16)((o[dt][r] * sA + vB * sB) * inv);
        }
        *(f16x4*)(crow + dt * 32 + g * 8 + hi * 4) = ov;
      }
    }
  }
}

extern "C" void kernel_launch(void* const* d_in, const int* in_sizes, int n_in,
                              void* d_out, int out_size, void* d_ws, size_t ws_size,
                              hipStream_t stream) {
  const float* q = (const float*)d_in[0];
  const float* k = (const float*)d_in[1];
  const float* v = (const float*)d_in[2];
  // d_in[3] = mask (causal tril, hardcoded), d_in[4] = max_seq_len (unused)
  const float* Wq = (const float*)d_in[5];
  const float* bq = (const float*)d_in[6];
  const float* Wk = (const float*)d_in[7];
  const float* bk = (const float*)d_in[8];
  const float* Wv = (const float*)d_in[9];
  const float* bv = (const float*)d_in[10];
  const float* Wo = (const float*)d_in[11];
  const float* bo = (const float*)d_in[12];

  char* ws = (char*)d_ws;
  const size_t MB = 1ull << 20;
  f16* qb   = (f16*)(ws + 0 * MB);    // [4096,1024] f16, 8MB each
  f16* kb   = (f16*)(ws + 8 * MB);
  f16* vb   = (f16*)(ws + 16 * MB);
  f16* Wqh  = (f16*)(ws + 24 * MB);   // [1024,1024] f16, 2MB each
  f16* Wkh  = (f16*)(ws + 26 * MB);
  f16* Wvh  = (f16*)(ws + 28 * MB);
  f16* Woh  = (f16*)(ws + 30 * MB);
  f16* Qh   = (f16*)(ws + 32 * MB);   // [B,H,S,64] f16
  f16* Kt   = (f16*)(ws + 40 * MB);   // [B,H,S/32,4,32,16] f16
  f16* Vt   = (f16*)(ws + 48 * MB);   // [B,H,S/16,64,16] f16
  f16* ctxb = (f16*)(ws + 56 * MB);   // [B,S,D] f16
  float2* rope2 = (float2*)(ws + 64 * MB);         // [S,32] (cos,sin)

  cvt_all_kernel<<<dim3(2048), dim3(256), 0, stream>>>(
      q, k, v, Wq, Wk, Wv, Wo, qb, kb, vb, Wqh, Wkh, Wvh, Woh, rope2);

  qkv_gemm_kernel<<<dim3(M_TOK / 128, D_MODEL / 128, 3), 256, 0, stream>>>(
      qb, kb, vb, Wqh, Wkh, Wvh, bq, bk, bv, Qh, Kt, Vt, rope2);

  attn_kernel<<<dim3(1024), dim3(256), 0, stream>>>(Qh, Kt, Vt, ctxb);

  out_gemm_kernel<<<dim3(M_TOK / 128, D_MODEL / 128), 256, 0, stream>>>(ctxb, Woh, bo, (float*)d_out);
}

// Round 13
// 121.247 us; speedup vs baseline: 1.1344x; 1.0149x over previous
//
#include <hip/hip_runtime.h>

#define S_LEN 2048
#define D_MODEL 1024
#define NH 16
#define BATCH 2
#define M_TOK 4096  // BATCH * S_LEN

typedef _Float16 f16;
typedef __attribute__((ext_vector_type(8))) _Float16 f16x8;
typedef __attribute__((ext_vector_type(4))) _Float16 f16x4;
typedef __attribute__((ext_vector_type(4))) float f32x4;
typedef __attribute__((ext_vector_type(16))) float f32x16;
typedef __attribute__((ext_vector_type(2))) unsigned int uint2v;

__device__ __forceinline__ void gl_lds16(const f16* g, f16* l) {
  __builtin_amdgcn_global_load_lds(
      (const __attribute__((address_space(1))) void*)g,
      (__attribute__((address_space(3))) void*)l, 16, 0, 0);
}

// ------- fused fp32 -> f16 convert for all 7 tensors + RoPE float2 table ----
__global__ void cvt_all_kernel(
    const float* __restrict__ q, const float* __restrict__ k, const float* __restrict__ v,
    const float* __restrict__ Wq, const float* __restrict__ Wk,
    const float* __restrict__ Wv, const float* __restrict__ Wo,
    f16* __restrict__ qb, f16* __restrict__ kb, f16* __restrict__ vb,
    f16* __restrict__ Wqh, f16* __restrict__ Wkh, f16* __restrict__ Wvh,
    f16* __restrict__ Woh, float2* __restrict__ rope2) {
  const int NX = (M_TOK * D_MODEL) / 4;    // float4 count per activation
  const int NW = (D_MODEL * D_MODEL) / 4;  // per weight
  const int total = 3 * NX + 4 * NW;
  int stride = gridDim.x * blockDim.x;
  int tid0 = blockIdx.x * blockDim.x + threadIdx.x;
  if (tid0 < S_LEN * 32) {
    int s = tid0 >> 5, i = tid0 & 31;
    float inv = powf(10000.0f, -(float)i * (1.0f / 16.0f));
    float ang = (float)s * inv;
    rope2[tid0] = make_float2(cosf(ang), sinf(ang));
  }
  for (int i = tid0; i < total; i += stride) {
    const float* src; f16* dst; int off;
    if (i < 3 * NX) {
      int ts = i / NX; off = i - ts * NX;
      src = ts == 0 ? q : ts == 1 ? k : v;
      dst = ts == 0 ? qb : ts == 1 ? kb : vb;
    } else {
      int j = i - 3 * NX;
      int ts = j / NW; off = j - ts * NW;
      src = ts == 0 ? Wq : ts == 1 ? Wk : ts == 2 ? Wv : Wo;
      dst = ts == 0 ? Wqh : ts == 1 ? Wkh : ts == 2 ? Wvh : Woh;
    }
    float4 vv = ((const float4*)src)[off];
    union { f16 h[4]; uint2 u; } o;
    o.h[0] = (f16)vv.x; o.h[1] = (f16)vv.y; o.h[2] = (f16)vv.z; o.h[3] = (f16)vv.w;
    ((uint2*)dst)[off] = o.u;
  }
}

// LDS swizzle (T2): LDS (row R, 16B-unit U) holds global unit U ^ ((R>>1)&3).
// Source side: unit (t&3) ^ ((t>>3)&3) [lane-constant]; read side:
// lkp = ((l>>4) ^ ((l>>1)&3)) * 8. Conflicts 3.15M -> 0 (R10).

// ---------------- fused Q/K/V projection GEMM (2-phase pipelined) ----------
// blockIdx.z epilogues:
//   0 = Q + RoPE -> row-major [B,H,S,64]
//   1 = K + RoPE -> fragment-linear [B,H,S/32,4(ks),32(k),16(d)]
//   2 = V        -> fragment-linear [B,H,S/16,64(d),16(k)], f16x4 stores
__global__ __launch_bounds__(256) void qkv_gemm_kernel(
    const f16* __restrict__ qb, const f16* __restrict__ kb, const f16* __restrict__ vb,
    const f16* __restrict__ Wqh, const f16* __restrict__ Wkh, const f16* __restrict__ Wvh,
    const float* __restrict__ bq, const float* __restrict__ bk, const float* __restrict__ bv,
    f16* __restrict__ Qh, f16* __restrict__ Kt, f16* __restrict__ Vt,
    const float2* __restrict__ rope2) {
  constexpr int K = D_MODEL;
  const int z = blockIdx.z;
  const f16* A = z == 0 ? qb : z == 1 ? kb : vb;
  const f16* Bm = z == 0 ? Wqh : z == 1 ? Wkh : Wvh;
  const float* bias = z == 0 ? bq : z == 1 ? bk : bv;

  __shared__ f16 As[2][128 * 32];
  __shared__ f16 Bs[2][128 * 32];
  const int t = threadIdx.x, w = t >> 6, l = t & 63;
  const int bm = blockIdx.x, bn = blockIdx.y;
  const int wr = w >> 1, wc = w & 1;
  const int lr = l & 15;
  const int lkp = (((l >> 4) ^ ((l >> 1) & 3)) * 8);  // swizzled read unit

  f32x4 acc[4][4] = {};

  const int su = (((t & 3) ^ ((t >> 3) & 3)) * 8);    // swizzled source unit
  // persistent staging pointers (advance by 32 each K-step; no recompute)
  const f16* gA0 = A + (size_t)(bm * 128 + (t >> 2)) * K + su;
  const f16* gA1 = gA0 + (size_t)64 * K;
  const f16* gB0 = Bm + (size_t)(bn * 128 + (t >> 2)) * K + su;
  const f16* gB1 = gB0 + (size_t)64 * K;
  f16* const pA0 = &As[0][w * 512]; f16* const pA1 = &As[1][w * 512];
  f16* const pB0 = &Bs[0][w * 512]; f16* const pB1 = &Bs[1][w * 512];

  auto stage = [&](int buf) {
    f16* a0 = buf ? pA1 : pA0;
    f16* b0 = buf ? pB1 : pB0;
    gl_lds16(gA0, a0);
    gl_lds16(gA1, a0 + 2048);
    gl_lds16(gB0, b0);
    gl_lds16(gB1, b0 + 2048);
  };

  stage(0);
  __syncthreads();
  for (int ti = 0; ti < 32; ++ti) {
    int cur = ti & 1;
    if (ti + 1 < 32) {
      gA0 += 32; gA1 += 32; gB0 += 32; gB1 += 32;
      stage(cur ^ 1);  // overlap with compute below
    }
    const f16* Ab = cur ? As[1] : As[0];
    const f16* Bb = cur ? Bs[1] : Bs[0];
    f16x8 af[4], bf[4];
#pragma unroll
    for (int m = 0; m < 4; m++) af[m] = *(const f16x8*)&Ab[(wr * 64 + m * 16 + lr) * 32 + lkp];
#pragma unroll
    for (int n = 0; n < 4; n++) bf[n] = *(const f16x8*)&Bb[(wc * 64 + n * 16 + lr) * 32 + lkp];
#pragma unroll
    for (int m = 0; m < 4; m++)
#pragma unroll
      for (int n = 0; n < 4; n++)
        acc[m][n] = __builtin_amdgcn_mfma_f32_16x16x32_f16(af[m], bf[n], acc[m][n], 0, 0, 0);
    __syncthreads();
  }

  // epilogue: C layout per 16x16 tile: col = lane&15, row = (lane>>4)*4 + j
#pragma unroll
  for (int m = 0; m < 4; m++) {
    int rbase = bm * 128 + wr * 64 + m * 16 + ((l >> 4) << 2);
#pragma unroll
    for (int n = 0; n < 4; n++) {
      int c = bn * 128 + wc * 64 + n * 16 + lr;
      float bv_ = bias[c];
      if (z == 2) {
        int s0 = rbase;
        int b = s0 >> 11, s = s0 & (S_LEN - 1);
        int h = c >> 6, dk = c & 63;
        int bh = b * NH + h;
        f16x4 ov;
#pragma unroll
        for (int j = 0; j < 4; j++) ov[j] = (f16)(acc[m][n][j] + bv_);
        *(f16x4*)&Vt[((((size_t)bh * (S_LEN / 16) + (s >> 4)) * 64) + dk) * 16 + (s & 15)] = ov;
      } else {
#pragma unroll
        for (int j = 0; j < 4; j++) {
          float x = acc[m][n][j] + bv_;
          int rr = rbase + j;
          int b = rr >> 11, s = rr & (S_LEN - 1);
          int h = c >> 6, dk = c & 63;
          int bh = b * NH + h;
          float p = __shfl_xor(x, 1);  // pair partner (col ^ 1)
          float2 cs = rope2[s * 32 + (dk >> 1)];
          float ov = (dk & 1) ? (p * cs.y + x * cs.x) : (x * cs.x - p * cs.y);
          if (z == 0) {
            Qh[(((size_t)bh) * S_LEN + s) * 64 + dk] = (f16)ov;
          } else {
            Kt[(((((size_t)bh * 64 + (s >> 5)) * 4 + (dk >> 4)) * 32) + (s & 31)) * 16 + (dk & 15)] = (f16)ov;
          }
        }
      }
    }
  }
}

// ---------------- output GEMM: fp32 out, 64x128 tile ----------------
// Tile 64x128 (was 128x128): grid 64x8 = 512 blocks = 2/CU = 8 waves/CU
// (old: 256 blocks = 1/CU = 4 waves/CU, 12.5% occupancy ceiling — the
// binding constraint for this kernel). Wave tile 32x64, acc[2][4].
__global__ __launch_bounds__(256) void out_gemm_kernel(
    const f16* __restrict__ A, const f16* __restrict__ Bm,
    const float* __restrict__ bias, float* __restrict__ Cout) {
  constexpr int N = D_MODEL, K = D_MODEL;
  __shared__ f16 As[2][64 * 32];
  __shared__ f16 Bs[2][128 * 32];
  const int t = threadIdx.x, w = t >> 6, l = t & 63;
  const int bm = blockIdx.x, bn = blockIdx.y;
  const int wr = w >> 1, wc = w & 1;   // wr: 32-row half, wc: 64-col half
  const int lr = l & 15;
  const int lkp = (((l >> 4) ^ ((l >> 1) & 3)) * 8);

  f32x4 acc[2][4] = {};

  const int su = (((t & 3) ^ ((t >> 3) & 3)) * 8);
  const f16* gA0 = A + (size_t)(bm * 64 + (t >> 2)) * K + su;
  const f16* gB0 = Bm + (size_t)(bn * 128 + (t >> 2)) * K + su;
  const f16* gB1 = gB0 + (size_t)64 * K;
  f16* const pA0 = &As[0][w * 512]; f16* const pA1 = &As[1][w * 512];
  f16* const pB0 = &Bs[0][w * 512]; f16* const pB1 = &Bs[1][w * 512];

  auto stage = [&](int buf) {
    f16* a0 = buf ? pA1 : pA0;
    f16* b0 = buf ? pB1 : pB0;
    gl_lds16(gA0, a0);
    gl_lds16(gB0, b0);
    gl_lds16(gB1, b0 + 2048);
  };

  stage(0);
  __syncthreads();
  for (int ti = 0; ti < 32; ++ti) {
    int cur = ti & 1;
    if (ti + 1 < 32) {
      gA0 += 32; gB0 += 32; gB1 += 32;
      stage(cur ^ 1);
    }
    const f16* Ab = cur ? As[1] : As[0];
    const f16* Bb = cur ? Bs[1] : Bs[0];
    f16x8 af[2], bf[4];
#pragma unroll
    for (int m = 0; m < 2; m++) af[m] = *(const f16x8*)&Ab[(wr * 32 + m * 16 + lr) * 32 + lkp];
#pragma unroll
    for (int n = 0; n < 4; n++) bf[n] = *(const f16x8*)&Bb[(wc * 64 + n * 16 + lr) * 32 + lkp];
#pragma unroll
    for (int m = 0; m < 2; m++)
#pragma unroll
      for (int n = 0; n < 4; n++)
        acc[m][n] = __builtin_amdgcn_mfma_f32_16x16x32_f16(af[m], bf[n], acc[m][n], 0, 0, 0);
    __syncthreads();
  }

#pragma unroll
  for (int m = 0; m < 2; m++) {
    int rbase = bm * 64 + wr * 32 + m * 16 + ((l >> 4) << 2);
#pragma unroll
    for (int n = 0; n < 4; n++) {
      int c = bn * 128 + wc * 64 + n * 16 + lr;
      float bv = bias[c];
#pragma unroll
      for (int j = 0; j < 4; j++)
        Cout[(size_t)(rbase + j) * N + c] = acc[m][n][j] + bv;
    }
  }
}

// ---------------- causal flash attention, swapped-QK^T 32x32 ----------------
// Qh: [B,H,S,64]; Kt: [B,H,S/32,4,32,16]; Vt: [B,H,S/16,64,16] (all f16).
// Coalesced 1KB K/V wave-loads. Grid 1024, 4 waves. Chunk pair (cx, 63-cx):
// 65 tiles/block uniform. Waves {0,1} k-split cx; {2,3} 63-cx; LDS merges.
// XCD-pinned bh. T5 setprio. Cross-half reduces: __shfl_xor(.,32) ONLY —
// permlane32_swap with duplicated operand is broken (R8+R12, absmax 2.19
// both times); the distinct-operand P-pack usage below is verified-correct.
__global__ __launch_bounds__(256, 4) void attn_kernel(
    const f16* __restrict__ Qh, const f16* __restrict__ Kt,
    const f16* __restrict__ Vt, f16* __restrict__ ctx) {
  __shared__ f16 po_lds[2][64][32];  // per pair: k-split partner partial O (f16)
  __shared__ float ml_lds[2][64];    // per pair: m[32], l[32]
  const int t = threadIdx.x, w = t >> 6, l = t & 63;
  const int lq = l & 31, hi = l >> 5;
  const int id = blockIdx.x;
  const int xcd = id & 7, slot = id >> 3;     // slot 0..127
  const int bh = (slot >> 5) * 8 + xcd;       // 4 bh per XCD
  const int b = bh >> 4, h = bh & 15;
  const int cp = slot & 31;                   // chunk-pair index
  const int pairidx = w >> 1, wk = w & 1;
  const int cx = pairidx ? (63 - cp) : cp;    // this wave-pair's q-chunk
  const int q0w = cx * 32;
  const int q = q0w + lq;
  const int ntot = cx + 1;                    // causal k-tiles for this chunk
  const int nA = (ntot + 1) >> 1;
  const int t0 = wk ? nA : 0;
  const int t1 = wk ? ntot : nA;

  const f16* Qb = Qh + ((size_t)bh * S_LEN + q0w) * 64;
  const f16* Kb = Kt + (size_t)bh * S_LEN * 64;   // tile stride 4*32*16 = 2048
  const f16* Vb = Vt + (size_t)bh * S_LEN * 64;   // kb2 stride 64*16 = 1024

  // Q as B-frag, pre-scaled by (1/8)*log2(e) -> softmax in exp2 domain
  f16x8 qf[4];
#pragma unroll
  for (int ks = 0; ks < 4; ks++) {
    qf[ks] = *(const f16x8*)(Qb + (size_t)lq * 64 + ks * 16 + hi * 8);
#pragma unroll
    for (int j = 0; j < 8; j++) qf[ks][j] *= (f16)0.18033688f;
  }

  f32x16 o[2] = {};  // O^T accum: o[dt][r] = O[d = dt*32 + (r&3)+8*(r>>2)+4*hi][q]
  float m = -1e30f, lsum = 0.f;

  auto loadK = [&](int kt, f16x8* dst) {
    const f16* kp = Kb + (size_t)kt * 2048 + lq * 16 + hi * 8;
#pragma unroll
    for (int ks = 0; ks < 4; ks++)
      dst[ks] = *(const f16x8*)(kp + ks * 512);
  };

  auto body = [&](int kt, f16x8* cur, f16x8* nxt) {
    const int k0 = kt * 32;
    loadK(kt + 1 < t1 ? kt + 1 : kt, nxt);  // prefetch next K tile
    // ---- QK^T (swapped): 4 contraction slices over DK=64
    f32x16 s = {};
    __builtin_amdgcn_s_setprio(1);
#pragma unroll
    for (int ks = 0; ks < 4; ks++)
      s = __builtin_amdgcn_mfma_f32_32x32x16_f16(cur[ks], qf[ks], s, 0, 0, 0);
    __builtin_amdgcn_s_setprio(0);
    // V-frags: coalesced 1KB loads, issued early (softmax covers latency)
    const f16* vp = Vb + (size_t)(k0 >> 4) * 1024 + lq * 16 + hi * 8;
    f16x8 vf00 = *(const f16x8*)(vp);                 // d=lq,    k=k0..k0+15
    f16x8 vf10 = *(const f16x8*)(vp + 512);           // d=32+lq
    f16x8 vf01 = *(const f16x8*)(vp + 1024);          // d=lq,    k=k0+16..k0+31
    f16x8 vf11 = *(const f16x8*)(vp + 1536);          // d=32+lq

    // ---- causal mask (diagonal tile only)
    if (kt == cx) {
#pragma unroll
      for (int r = 0; r < 16; r++) {
        int kk = k0 + (r & 3) + 8 * (r >> 2) + 4 * hi;
        if (kk > q) s[r] = -1e30f;
      }
    }
    // ---- online softmax (exp2 domain), balanced-tree reductions
    float a0 = fmaxf(s[0], s[1]), a1 = fmaxf(s[2], s[3]);
    float a2 = fmaxf(s[4], s[5]), a3 = fmaxf(s[6], s[7]);
    float a4 = fmaxf(s[8], s[9]), a5 = fmaxf(s[10], s[11]);
    float a6 = fmaxf(s[12], s[13]), a7 = fmaxf(s[14], s[15]);
    float b0_ = fmaxf(a0, a1), b1_ = fmaxf(a2, a3), b2_ = fmaxf(a4, a5), b3_ = fmaxf(a6, a7);
    float pmax = fmaxf(fmaxf(b0_, b1_), fmaxf(b2_, b3_));
    pmax = fmaxf(pmax, __shfl_xor(pmax, 32));
    if (!__all(pmax <= m + 11.5f)) {  // defer-max (T13), THR = 8*log2e
      float mn = fmaxf(m, pmax);
      float sc = exp2f(m - mn);
#pragma unroll
      for (int r = 0; r < 16; r++) { o[0][r] *= sc; o[1][r] *= sc; }
      lsum *= sc;
      m = mn;
    }
#pragma unroll
    for (int r = 0; r < 16; r++) s[r] = exp2f(s[r] - m);
    float c0 = (s[0] + s[1]) + (s[2] + s[3]);
    float c1 = (s[4] + s[5]) + (s[6] + s[7]);
    float c2 = (s[8] + s[9]) + (s[10] + s[11]);
    float c3 = (s[12] + s[13]) + (s[14] + s[15]);
    float rs = (c0 + c1) + (c2 + c3);
    rs += __shfl_xor(rs, 32);
    lsum += rs;

    // ---- pack P into PV B-frag: 8 cvt_pkrtz + 4 permlane32_swap
    unsigned pw[8];
#pragma unroll
    for (int i = 0; i < 8; i++)
      pw[i] = __builtin_bit_cast(unsigned, __builtin_amdgcn_cvt_pkrtz(s[2 * i], s[2 * i + 1]));
    uint2v s02 = __builtin_amdgcn_permlane32_swap(pw[0], pw[2], false, false);
    uint2v s13 = __builtin_amdgcn_permlane32_swap(pw[1], pw[3], false, false);
    uint2v s46 = __builtin_amdgcn_permlane32_swap(pw[4], pw[6], false, false);
    uint2v s57 = __builtin_amdgcn_permlane32_swap(pw[5], pw[7], false, false);
    union BU { unsigned u[4]; f16x8 v; };
    BU pb0, pb1;
    pb0.u[0] = s02[0]; pb0.u[1] = s13[0]; pb0.u[2] = s02[1]; pb0.u[3] = s13[1];
    pb1.u[0] = s46[0]; pb1.u[1] = s57[0]; pb1.u[2] = s46[1]; pb1.u[3] = s57[1];

    // ---- PV: O^T += V^T-frag x P^T-frag
    __builtin_amdgcn_s_setprio(1);
    o[0] = __builtin_amdgcn_mfma_f32_32x32x16_f16(vf00, pb0.v, o[0], 0, 0, 0);
    o[0] = __builtin_amdgcn_mfma_f32_32x32x16_f16(vf01, pb1.v, o[0], 0, 0, 0);
    o[1] = __builtin_amdgcn_mfma_f32_32x32x16_f16(vf10, pb0.v, o[1], 0, 0, 0);
    o[1] = __builtin_amdgcn_mfma_f32_32x32x16_f16(vf11, pb1.v, o[1], 0, 0, 0);
    __builtin_amdgcn_s_setprio(0);
  };

  f16x8 ka[4], kb_[4];
  if (t0 < t1) loadK(t0, ka);
  int kt = t0;
  for (; kt + 2 <= t1; kt += 2) { body(kt, ka, kb_); body(kt + 1, kb_, ka); }
  if (kt < t1) body(kt, ka, kb_);

  // ---- k-split partner publishes, lead wave merges + writes
  if (wk == 1) {
#pragma unroll
    for (int dt = 0; dt < 2; dt++)
#pragma unroll
      for (int r = 0; r < 16; r++)
        po_lds[pairidx][(dt * 16 + r) * 2 + hi][lq] = (f16)o[dt][r];
    if (hi == 0) { ml_lds[pairidx][lq] = m; ml_lds[pairidx][32 + lq] = lsum; }
  }
  __syncthreads();
  if (wk == 0) {
    float mB = ml_lds[pairidx][lq], lB = ml_lds[pairidx][32 + lq];
    float mf = fmaxf(m, mB);
    float sA = exp2f(m - mf), sB = exp2f(mB - mf);
    float lf = lsum * sA + lB * sB;
    float inv = 1.0f / lf;
    f16* crow = ctx + ((size_t)(b * S_LEN + q)) * D_MODEL + h * 64;
#pragma unroll
    for (int dt = 0; dt < 2; dt++) {
#pragma unroll
      for (int g = 0; g < 4; g++) {
        f16x4 ov;
#pragma unroll
        for (int c = 0; c < 4; c++) {
          int r = g * 4 + c;
          float vB = (float)po_lds[pairidx][(dt * 16 + r) * 2 + hi][lq];
          ov[c] = (f16)((o[dt][r] * sA + vB * sB) * inv);
        }
        *(f16x4*)(crow + dt * 32 + g * 8 + hi * 4) = ov;
      }
    }
  }
}

extern "C" void kernel_launch(void* const* d_in, const int* in_sizes, int n_in,
                              void* d_out, int out_size, void* d_ws, size_t ws_size,
                              hipStream_t stream) {
  const float* q = (const float*)d_in[0];
  const float* k = (const float*)d_in[1];
  const float* v = (const float*)d_in[2];
  // d_in[3] = mask (causal tril, hardcoded), d_in[4] = max_seq_len (unused)
  const float* Wq = (const float*)d_in[5];
  const float* bq = (const float*)d_in[6];
  const float* Wk = (const float*)d_in[7];
  const float* bk = (const float*)d_in[8];
  const float* Wv = (const float*)d_in[9];
  const float* bv = (const float*)d_in[10];
  const float* Wo = (const float*)d_in[11];
  const float* bo = (const float*)d_in[12];

  char* ws = (char*)d_ws;
  const size_t MB = 1ull << 20;
  f16* qb   = (f16*)(ws + 0 * MB);    // [4096,1024] f16, 8MB each
  f16* kb   = (f16*)(ws + 8 * MB);
  f16* vb   = (f16*)(ws + 16 * MB);
  f16* Wqh  = (f16*)(ws + 24 * MB);   // [1024,1024] f16, 2MB each
  f16* Wkh  = (f16*)(ws + 26 * MB);
  f16* Wvh  = (f16*)(ws + 28 * MB);
  f16* Woh  = (f16*)(ws + 30 * MB);
  f16* Qh   = (f16*)(ws + 32 * MB);   // [B,H,S,64] f16
  f16* Kt   = (f16*)(ws + 40 * MB);   // [B,H,S/32,4,32,16] f16
  f16* Vt   = (f16*)(ws + 48 * MB);   // [B,H,S/16,64,16] f16
  f16* ctxb = (f16*)(ws + 56 * MB);   // [B,S,D] f16
  float2* rope2 = (float2*)(ws + 64 * MB);         // [S,32] (cos,sin)

  cvt_all_kernel<<<dim3(2048), dim3(256), 0, stream>>>(
      q, k, v, Wq, Wk, Wv, Wo, qb, kb, vb, Wqh, Wkh, Wvh, Woh, rope2);

  qkv_gemm_kernel<<<dim3(M_TOK / 128, D_MODEL / 128, 3), 256, 0, stream>>>(
      qb, kb, vb, Wqh, Wkh, Wvh, bq, bk, bv, Qh, Kt, Vt, rope2);

  attn_kernel<<<dim3(1024), dim3(256), 0, stream>>>(Qh, Kt, Vt, ctxb);

  out_gemm_kernel<<<dim3(M_TOK / 64, D_MODEL / 128), 256, 0, stream>>>(ctxb, Woh, bo, (float*)d_out);
}